// Round 7
// baseline (1078.534 us; speedup 1.0000x reference)
//
#include <hip/hip_runtime.h>
#include <hip/hip_bf16.h>
#include <math.h>

typedef unsigned short u16;
typedef short bf16x8 __attribute__((ext_vector_type(8)));
typedef float f32x4 __attribute__((ext_vector_type(4)));

#define Bz 64
#define Tt 4096
#define Cin 64
#define K1c 128
#define Hh 96
#define T2 1024
#define G4 384
#define NC 109

#define MFMA16(a, b, c) __builtin_amdgcn_mfma_f32_16x16x32_bf16(a, b, c, 0, 0, 0)

__device__ __forceinline__ float bf2f(u16 v) {
  union { unsigned int u; float f; } x; x.u = ((unsigned int)v) << 16; return x.f;
}
__device__ __forceinline__ u16 f2bf(float f) {
  union { unsigned int u; float f; } x; x.f = f;
  unsigned int u = x.u;
  unsigned int r = u + 0x7fff + ((u >> 16) & 1);
  return (u16)(r >> 16);
}
__device__ __forceinline__ float dpp_xor1(float x) {
  int r = __builtin_amdgcn_mov_dpp(__float_as_int(x), 0xB1, 0xF, 0xF, true);
  return __int_as_float(r);
}
__device__ __forceinline__ float dpp_xor2(float x) {
  int r = __builtin_amdgcn_mov_dpp(__float_as_int(x), 0x4E, 0xF, 0xF, true);
  return __int_as_float(r);
}

// ---------------- K0: weight packing + BN folding ----------------
__global__ void k_prep(const float* __restrict__ w1, const float* __restrict__ cb1,
                       const float* __restrict__ g1, const float* __restrict__ b1,
                       const float* __restrict__ m1, const float* __restrict__ v1,
                       const float* __restrict__ w2, const float* __restrict__ cb2,
                       const float* __restrict__ g2, const float* __restrict__ b2,
                       const float* __restrict__ m2, const float* __restrict__ v2,
                       const float* __restrict__ wr, const float* __restrict__ cbr,
                       const float* __restrict__ gr, const float* __restrict__ br,
                       const float* __restrict__ mr, const float* __restrict__ vr,
                       const float* __restrict__ wx, const float* __restrict__ sbia,
                       u16* __restrict__ w1b, u16* __restrict__ w2b,
                       u16* __restrict__ wrb, float* __restrict__ wxT,
                       float* __restrict__ bperm,
                       float* __restrict__ al1, float* __restrict__ be1,
                       float* __restrict__ al2, float* __restrict__ be2,
                       float* __restrict__ alr, float* __restrict__ ber)
{
  int tid = blockIdx.x * blockDim.x + threadIdx.x;
  int nth = gridDim.x * blockDim.x;
  // w1b[o*448 + kt*64 + c] = bf16(w1[o][c][kt])
  for (int idx = tid; idx < 128 * 448; idx += nth) {
    int o = idx / 448, k = idx % 448;
    int kt = k >> 6, c = k & 63;
    w1b[idx] = f2bf(w1[(o * 64 + c) * 7 + kt]);
  }
  // w2b[o*384 + kk*128 + c] = bf16(w2[o][c][kk])
  for (int idx = tid; idx < 96 * 384; idx += nth) {
    int o = idx / 384, k = idx % 384;
    int kk = k >> 7, c = k & 127;
    w2b[idx] = f2bf(w2[(o * 128 + c) * 3 + kk]);
  }
  // wrb[o*128 + c] = bf16(wr[o][c])
  for (int idx = tid; idx < 96 * 128; idx += nth) {
    wrb[idx] = f2bf(wr[idx]);
  }
  // wxT[h*384 + (ch*4+g)] = wx[g*96+ch][h]  (permuted: ch-major gate packing)
  for (int idx = tid; idx < 96 * 384; idx += nth) {
    int c = idx % 384, h = idx / 384;
    int ch = c >> 2, g = c & 3;
    wxT[idx] = wx[((size_t)(g * 96 + ch)) * 96 + h];
  }
  // bperm[ch*4+g] = sbia[g*96+ch]
  for (int c = tid; c < 384; c += nth) {
    int ch = c >> 2, g = c & 3;
    bperm[c] = sbia[g * 96 + ch];
  }
  for (int o = tid; o < 128; o += nth) {
    float a = g1[o] / sqrtf(v1[o] + 1e-5f);
    al1[o] = a; be1[o] = b1[o] + (cb1[o] - m1[o]) * a;
  }
  for (int o = tid; o < 96; o += nth) {
    float a = g2[o] / sqrtf(v2[o] + 1e-5f);
    al2[o] = a; be2[o] = b2[o] + (cb2[o] - m2[o]) * a;
    float ar = gr[o] / sqrtf(vr[o] + 1e-5f);
    alr[o] = ar; ber[o] = br[o] + (cbr[o] - mr[o]) * ar;
  }
}

// ---------------- K1: conv1 MFMA implicit GEMM (unchanged) ----------------
__launch_bounds__(256, 2)
__global__ void k_conv1(const float* __restrict__ x, const u16* __restrict__ w1b,
                        const float* __restrict__ al1, const float* __restrict__ be1,
                        u16* __restrict__ out1)
{
  __shared__ __align__(16) u16 xs[134 * 72];
  int tid = threadIdx.x;
  int b = blockIdx.y;
  int t0 = blockIdx.x * 128;
  const float* xb = x + (size_t)b * Tt * Cin;

  for (int idx = tid; idx < 134 * 16; idx += 256) {
    int row = idx >> 4, c4 = (idx & 15) << 2;
    int gt = t0 - 3 + row;
    float4 v = make_float4(0.f, 0.f, 0.f, 0.f);
    if (gt >= 0 && gt < Tt) v = *(const float4*)(xb + (size_t)gt * 64 + c4);
    ushort4 s;
    s.x = f2bf(v.x); s.y = f2bf(v.y); s.z = f2bf(v.z); s.w = f2bf(v.w);
    *(ushort4*)(xs + row * 72 + c4) = s;
  }
  __syncthreads();

  int l = tid & 63;
  int wid = tid >> 6;
  int wm = wid >> 1, wn = wid & 1;
  int lr = l & 15, g = l >> 4;

  f32x4 acc[4][4];
#pragma unroll
  for (int i = 0; i < 4; i++)
#pragma unroll
    for (int j = 0; j < 4; j++) acc[i][j] = (f32x4){0.f, 0.f, 0.f, 0.f};

  const u16* wbase = w1b + (size_t)(wn * 64 + lr) * 448;

  for (int s = 0; s < 14; ++s) {
    int kt = s >> 1;
    int cofs = ((s & 1) << 5) + (g << 3);
    const u16* xrow = xs + (wm * 64 + lr + kt) * 72 + cofs;
    bf16x8 a0 = *(const bf16x8*)(xrow);
    bf16x8 a1 = *(const bf16x8*)(xrow + 16 * 72);
    bf16x8 a2 = *(const bf16x8*)(xrow + 32 * 72);
    bf16x8 a3 = *(const bf16x8*)(xrow + 48 * 72);
    int ko = (s << 5) + (g << 3);
    bf16x8 b0 = *(const bf16x8*)(wbase + ko);
    bf16x8 b1 = *(const bf16x8*)(wbase + 16 * 448 + ko);
    bf16x8 b2 = *(const bf16x8*)(wbase + 32 * 448 + ko);
    bf16x8 b3 = *(const bf16x8*)(wbase + 48 * 448 + ko);
    acc[0][0] = MFMA16(a0, b0, acc[0][0]);
    acc[0][1] = MFMA16(a0, b1, acc[0][1]);
    acc[0][2] = MFMA16(a0, b2, acc[0][2]);
    acc[0][3] = MFMA16(a0, b3, acc[0][3]);
    acc[1][0] = MFMA16(a1, b0, acc[1][0]);
    acc[1][1] = MFMA16(a1, b1, acc[1][1]);
    acc[1][2] = MFMA16(a1, b2, acc[1][2]);
    acc[1][3] = MFMA16(a1, b3, acc[1][3]);
    acc[2][0] = MFMA16(a2, b0, acc[2][0]);
    acc[2][1] = MFMA16(a2, b1, acc[2][1]);
    acc[2][2] = MFMA16(a2, b2, acc[2][2]);
    acc[2][3] = MFMA16(a2, b3, acc[2][3]);
    acc[3][0] = MFMA16(a3, b0, acc[3][0]);
    acc[3][1] = MFMA16(a3, b1, acc[3][1]);
    acc[3][2] = MFMA16(a3, b2, acc[3][2]);
    acc[3][3] = MFMA16(a3, b3, acc[3][3]);
  }

  int colb = wn * 64 + lr;
  int rowb = t0 + wm * 64 + (l >> 4) * 4;
#pragma unroll
  for (int nf = 0; nf < 4; nf++) {
    int col = colb + nf * 16;
    float A = al1[col], Bt = be1[col];
#pragma unroll
    for (int mf = 0; mf < 4; mf++) {
      int row = rowb + mf * 16;
#pragma unroll
      for (int r = 0; r < 4; r++) {
        float v = acc[mf][nf][r];
        v = fmaxf(v * A + Bt, 0.f);
        out1[((size_t)b * Tt + row + r) * 128 + col] = f2bf(v);
      }
    }
  }
}

// ---------------- K2: conv2 MFMA implicit GEMM + fused residual (unchanged) ----------------
__launch_bounds__(256, 4)
__global__ void k_conv2(const u16* __restrict__ out1, const u16* __restrict__ w2b,
                        const u16* __restrict__ wrb,
                        const float* __restrict__ al2, const float* __restrict__ be2,
                        const float* __restrict__ alr, const float* __restrict__ ber,
                        float* __restrict__ seq)
{
  int tid = threadIdx.x;
  int b = blockIdx.y;
  int t20 = blockIdx.x * 64;
  int l = tid & 63;
  int wid = tid >> 6;
  int wm = wid >> 1, wn = wid & 1;    // wave tile 32 x 48
  int lr = l & 15, g = l >> 4;

  f32x4 acc[2][3], accr[2][3];
#pragma unroll
  for (int i = 0; i < 2; i++)
#pragma unroll
    for (int j = 0; j < 3; j++) {
      acc[i][j] = (f32x4){0.f, 0.f, 0.f, 0.f};
      accr[i][j] = (f32x4){0.f, 0.f, 0.f, 0.f};
    }

  const u16* ob = out1 + (size_t)b * Tt * 128;
  int colb = wn * 48 + lr;

#pragma unroll
  for (int f = 0; f < 12; f++) {
    int kk = f >> 2;
    int c = ((f & 3) << 5) + (g << 3);
    bf16x8 a[2];
#pragma unroll
    for (int mf = 0; mf < 2; mf++) {
      int t2 = t20 + wm * 32 + mf * 16 + lr;
      int gt = 4 * t2 + kk - 1;
      if (gt >= 0)
        a[mf] = *(const bf16x8*)(ob + (size_t)gt * 128 + c);
      else
        a[mf] = (bf16x8){0, 0, 0, 0, 0, 0, 0, 0};
    }
#pragma unroll
    for (int nf = 0; nf < 3; nf++) {
      int col = colb + nf * 16;
      bf16x8 bb = *(const bf16x8*)(w2b + (size_t)col * 384 + (f << 5) + (g << 3));
      acc[0][nf] = MFMA16(a[0], bb, acc[0][nf]);
      acc[1][nf] = MFMA16(a[1], bb, acc[1][nf]);
    }
    if (kk == 1) {
#pragma unroll
      for (int nf = 0; nf < 3; nf++) {
        int col = colb + nf * 16;
        bf16x8 br = *(const bf16x8*)(wrb + (size_t)col * 128 + ((f & 3) << 5) + (g << 3));
        accr[0][nf] = MFMA16(a[0], br, accr[0][nf]);
        accr[1][nf] = MFMA16(a[1], br, accr[1][nf]);
      }
    }
  }

  int rowb = t20 + wm * 32 + (l >> 4) * 4;
#pragma unroll
  for (int nf = 0; nf < 3; nf++) {
    int col = colb + nf * 16;
    float A = al2[col], Bt = be2[col];
    float Ar = alr[col], Br = ber[col];
#pragma unroll
    for (int mf = 0; mf < 2; mf++) {
      int row = rowb + mf * 16;
#pragma unroll
      for (int r = 0; r < 4; r++) {
        float v = fmaxf(acc[mf][nf][r] * A + Bt, 0.f) + accr[mf][nf][r] * Ar + Br;
        seq[((size_t)b * T2 + row + r) * 96 + col] = v;
      }
    }
  }
}

// ---------------- K3: pre = seq @ wxT + bias, fp32, zero-LDS (unchanged) ----------------
__launch_bounds__(256)
__global__ void k_pre(const float* __restrict__ seq, const float* __restrict__ wxT,
                      const float* __restrict__ bias, float* __restrict__ pre)
{
  int tid = threadIdx.x;
  int b = blockIdx.z, nt = blockIdx.y, t20 = blockIdx.x * 128;
  int g0 = nt * 128;
  int lane32 = tid & 31, col4 = lane32 * 4;
  int trow = (tid >> 5) * 16;

  const float* sb = seq + ((size_t)b * T2 + t20 + trow) * 96;
  const float* wb = wxT + g0 + col4;

  f32x4 acc[16];
#pragma unroll
  for (int r = 0; r < 16; r++) acc[r] = (f32x4){0.f, 0.f, 0.f, 0.f};

  for (int kb = 0; kb < 96; kb += 4) {
    f32x4 bw0 = *(const f32x4*)(wb + (size_t)(kb + 0) * 384);
    f32x4 bw1 = *(const f32x4*)(wb + (size_t)(kb + 1) * 384);
    f32x4 bw2 = *(const f32x4*)(wb + (size_t)(kb + 2) * 384);
    f32x4 bw3 = *(const f32x4*)(wb + (size_t)(kb + 3) * 384);
#pragma unroll
    for (int r = 0; r < 16; r++) {
      f32x4 av = *(const f32x4*)(sb + (size_t)r * 96 + kb);
      acc[r] += av.x * bw0;
      acc[r] += av.y * bw1;
      acc[r] += av.z * bw2;
      acc[r] += av.w * bw3;
    }
  }

  f32x4 b4 = *(const f32x4*)(bias + g0 + col4);
  float* pb = pre + ((size_t)b * T2 + t20 + trow) * 384 + g0 + col4;
#pragma unroll
  for (int r = 0; r < 16; r++) {
    *(f32x4*)(pb + (size_t)r * 384) = acc[r] + b4;
  }
}

// ---------------- K4: sLSTM recurrence v5 — two batches per block ----------------
// 512 threads = 8 waves. Waves 0-3: batch A (v3 layout), waves 4-7: batch B.
// Each SIMD hosts one wave of each batch (round-robin wave->SIMD), so one
// batch's FMA issue overlaps the other's pwbuf/exp/barrier latency.
// Within a batch: wave w owns channels [24w,24w+24); lane (q=lane>>2,j=lane&3)
// computes 6 rows (6q..6q+5, row=chl*4+gate) over K-slice [24j,24j+24);
// DPP quad reduce; preact publish via per-batch pwbuf (intra-wave DS FIFO);
// gate math in lanes 0..23; one shared __syncthreads per step (ping-pong hbuf).
__launch_bounds__(512, 1)
__global__ void k_slstm(const float* __restrict__ pre, const float* __restrict__ wh,
                        float* __restrict__ hsum)
{
  __shared__ __align__(16) float hbuf[2][2][96];   // [batch_local][pingpong][ch]
  __shared__ __align__(16) float pwbuf[2][4][96];  // [batch_local][wave][row]
  int tid = threadIdx.x;
  int bl = tid >> 8;          // batch_local 0/1
  int t8 = tid & 255;
  int b = blockIdx.x * 2 + bl;
  int w = t8 >> 6;            // wave within batch 0..3
  int lane = tid & 63;
  int q = lane >> 2, j = lane & 3;

  // weights: wq[a][kq] = wh[(g*96+ch)*96 + j*24 + ...], rows r=6q+a
  float4 wq[6][6];
#pragma unroll
  for (int a = 0; a < 6; a++) {
    int r = 6 * q + a;
    int chl = r >> 2, g = r & 3;
    int ch = w * 24 + chl;
    const float4* wrow = (const float4*)(wh + ((size_t)(g * 96 + ch)) * 96 + j * 24);
#pragma unroll
    for (int kq = 0; kq < 6; kq++) wq[a][kq] = wrow[kq];
  }

  bool gl = (lane < 24);
  float c = 0.f, n = 0.f, m = 0.f, hs = 0.f;
  if (t8 < 96) hbuf[bl][0][t8] = 0.f;
  __syncthreads();

  // px prefetch (gate lanes): float4 (z,i,f,o) for ch = w*24+lane
  const float4* pxp = (const float4*)(pre + (size_t)b * T2 * G4) + (w * 24 + lane);
  float4 pxA = make_float4(0, 0, 0, 0), pxB = pxA;
  if (gl) { pxA = pxp[0]; pxB = pxp[96]; }

  const float L2E = 1.44269504f;
  int p = 0;
  for (int t = 0; t < T2; t++) {
    float4 pxN = make_float4(0, 0, 0, 0);
    if (gl) {
      int tn = t + 2 < T2 ? t + 2 : T2 - 1;
      pxN = pxp[(size_t)tn * 96];
    }
    // h slice (6 x ds_read_b128, conflict-free broadcast within j-groups)
    float4 hq[6];
#pragma unroll
    for (int kq = 0; kq < 6; kq++) hq[kq] = *(const float4*)(&hbuf[bl][p][j * 24 + kq * 4]);

    float acc[6];
#pragma unroll
    for (int a = 0; a < 6; a++) {
      float s = 0.f;
#pragma unroll
      for (int kq = 0; kq < 6; kq++) {
        s += hq[kq].x * wq[a][kq].x;
        s += hq[kq].y * wq[a][kq].y;
        s += hq[kq].z * wq[a][kq].z;
        s += hq[kq].w * wq[a][kq].w;
      }
      s += dpp_xor1(s);
      s += dpp_xor2(s);
      acc[a] = s;
    }
    // intra-wave preact publish (j==0 lanes)
    if (j == 0) {
      *(float2*)(&pwbuf[bl][w][6 * q + 0]) = make_float2(acc[0], acc[1]);
      *(float2*)(&pwbuf[bl][w][6 * q + 2]) = make_float2(acc[2], acc[3]);
      *(float2*)(&pwbuf[bl][w][6 * q + 4]) = make_float2(acc[4], acc[5]);
    }
    asm volatile("" ::: "memory");  // keep DS order (per-wave LDS FIFO)
    if (gl) {
      float4 pa = *(const float4*)(&pwbuf[bl][w][lane * 4]);
      float zp = pa.x + pxA.x, ip = pa.y + pxA.y;
      float fp = pa.z + pxA.z, op = pa.w + pxA.w;
      float zc = fminf(fmaxf(zp, -30.f), 30.f);
      float ez = exp2f(zc * (2.f * L2E));
      float z = 1.f - 2.f * __builtin_amdgcn_rcpf(ez + 1.f);
      float oc = fminf(fmaxf(op, -30.f), 30.f);
      float o = __builtin_amdgcn_rcpf(1.f + exp2f(-oc * L2E));
      float mn = fmaxf(fp + m, ip);
      float iv = exp2f((ip - mn) * L2E);
      float fv = exp2f((fp + m - mn) * L2E);
      c = fv * c + iv * z;
      n = fv * n + iv;
      m = mn;
      float h = o * c * __builtin_amdgcn_rcpf(fmaxf(n, 1.f));
      hs += h;
      hbuf[bl][p ^ 1][w * 24 + lane] = h;
    }
    pxA = pxB; pxB = pxN;
    __syncthreads();
    p ^= 1;
  }
  if (gl) hsum[b * 96 + w * 24 + lane] = hs * (1.f / 1024.f);
}

// ---------------- K5: head (unchanged) ----------------
__launch_bounds__(128)
__global__ void k_head(const float* __restrict__ hsum, const float* __restrict__ fc1w,
                       const float* __restrict__ fc1b, const float* __restrict__ fc2w,
                       const float* __restrict__ fc2b, float* __restrict__ out)
{
  __shared__ float p[96];
  __shared__ float z1[128];
  int tid = threadIdx.x, b = blockIdx.x;
  if (tid < 96) p[tid] = hsum[b * 96 + tid];
  __syncthreads();
  {
    float a = fc1b[tid];
    const float* wr = fc1w + tid * 96;
    for (int h = 0; h < 96; h++) a += p[h] * wr[h];
    z1[tid] = fmaxf(a, 0.f);
  }
  __syncthreads();
  if (tid < NC) {
    float a = fc2b[tid];
    const float* wr = fc2w + tid * 128;
    for (int j = 0; j < 128; j++) a += z1[j] * wr[j];
    out[b * NC + tid] = a;
  }
}

extern "C" void kernel_launch(void* const* d_in, const int* in_sizes, int n_in,
                              void* d_out, int out_size, void* d_ws, size_t ws_size,
                              hipStream_t stream)
{
  const float* x    = (const float*)d_in[0];
  const float* w1   = (const float*)d_in[1];
  const float* cb1  = (const float*)d_in[2];
  const float* g1   = (const float*)d_in[3];
  const float* b1   = (const float*)d_in[4];
  const float* m1   = (const float*)d_in[5];
  const float* v1   = (const float*)d_in[6];
  const float* w2   = (const float*)d_in[7];
  const float* cb2  = (const float*)d_in[8];
  const float* g2   = (const float*)d_in[9];
  const float* b2   = (const float*)d_in[10];
  const float* m2   = (const float*)d_in[11];
  const float* v2   = (const float*)d_in[12];
  const float* wr   = (const float*)d_in[13];
  const float* cbr  = (const float*)d_in[14];
  const float* gr   = (const float*)d_in[15];
  const float* br   = (const float*)d_in[16];
  const float* mr   = (const float*)d_in[17];
  const float* vr   = (const float*)d_in[18];
  const float* wx   = (const float*)d_in[19];
  const float* wh   = (const float*)d_in[20];
  const float* sbia = (const float*)d_in[21];
  const float* fc1w = (const float*)d_in[22];
  const float* fc1b = (const float*)d_in[23];
  const float* fc2w = (const float*)d_in[24];
  const float* fc2b = (const float*)d_in[25];

  char* ws = (char*)d_ws;
  size_t off = 0;
  auto alloc = [&](size_t bytes) -> void* {
    void* p = (void*)(ws + off);
    off = (off + bytes + 255) & ~((size_t)255);
    return p;
  };
  u16*   out1 = (u16*)  alloc((size_t)Bz * Tt * K1c * 2);   // 67.1 MB
  float* seq  = (float*)alloc((size_t)Bz * T2 * Hh * 4);    // 25.2 MB
  float* pre  = (float*)alloc((size_t)Bz * T2 * G4 * 4);    // 100.7 MB
  u16*   w1b  = (u16*)  alloc(448 * 128 * 2);
  u16*   w2b  = (u16*)  alloc(96 * 384 * 2);
  u16*   wrb  = (u16*)  alloc(96 * 128 * 2);
  float* wxT  = (float*)alloc(96 * 384 * 4);
  float* bperm= (float*)alloc(384 * 4);
  float* al1  = (float*)alloc(128 * 4);
  float* be1  = (float*)alloc(128 * 4);
  float* al2  = (float*)alloc(96 * 4);
  float* be2  = (float*)alloc(96 * 4);
  float* alr  = (float*)alloc(96 * 4);
  float* ber  = (float*)alloc(96 * 4);
  float* hsum = (float*)alloc((size_t)Bz * Hh * 4);
  (void)ws_size; (void)in_sizes; (void)n_in; (void)out_size;

  k_prep<<<dim3(224), dim3(256), 0, stream>>>(
      w1, cb1, g1, b1, m1, v1, w2, cb2, g2, b2, m2, v2,
      wr, cbr, gr, br, mr, vr, wx, sbia,
      w1b, w2b, wrb, wxT, bperm, al1, be1, al2, be2, alr, ber);

  k_conv1<<<dim3(Tt / 128, Bz), dim3(256), 0, stream>>>(x, w1b, al1, be1, out1);

  k_conv2<<<dim3(T2 / 64, Bz), dim3(256), 0, stream>>>(out1, w2b, wrb, al2, be2, alr, ber, seq);

  k_pre<<<dim3(T2 / 128, 3, Bz), dim3(256), 0, stream>>>(seq, wxT, bperm, pre);

  k_slstm<<<dim3(Bz / 2), dim3(512), 0, stream>>>(pre, wh, hsum);

  k_head<<<dim3(Bz), dim3(128), 0, stream>>>(hsum, fc1w, fc1b, fc2w, fc2b, (float*)d_out);
}

// Round 9
// 826.726 us; speedup vs baseline: 1.3046x; 1.3046x over previous
//
#include <hip/hip_runtime.h>
#include <hip/hip_bf16.h>
#include <math.h>

typedef unsigned short u16;
typedef short bf16x8 __attribute__((ext_vector_type(8)));
typedef float f32x4 __attribute__((ext_vector_type(4)));

#define Bz 64
#define Tt 4096
#define Cin 64
#define K1c 128
#define Hh 96
#define T2 1024
#define G4 384
#define NC 109

#define MFMA16(a, b, c) __builtin_amdgcn_mfma_f32_16x16x32_bf16(a, b, c, 0, 0, 0)

__device__ __forceinline__ float bf2f(u16 v) {
  union { unsigned int u; float f; } x; x.u = ((unsigned int)v) << 16; return x.f;
}
__device__ __forceinline__ u16 f2bf(float f) {
  union { unsigned int u; float f; } x; x.f = f;
  unsigned int u = x.u;
  unsigned int r = u + 0x7fff + ((u >> 16) & 1);
  return (u16)(r >> 16);
}

// ---------------- K0: weight packing + BN folding ----------------
__global__ void k_prep(const float* __restrict__ w1, const float* __restrict__ cb1,
                       const float* __restrict__ g1, const float* __restrict__ b1,
                       const float* __restrict__ m1, const float* __restrict__ v1,
                       const float* __restrict__ w2, const float* __restrict__ cb2,
                       const float* __restrict__ g2, const float* __restrict__ b2,
                       const float* __restrict__ m2, const float* __restrict__ v2,
                       const float* __restrict__ wr, const float* __restrict__ cbr,
                       const float* __restrict__ gr, const float* __restrict__ br,
                       const float* __restrict__ mr, const float* __restrict__ vr,
                       const float* __restrict__ wx, const float* __restrict__ sbia,
                       const float* __restrict__ wh,
                       u16* __restrict__ w1b, u16* __restrict__ w2b,
                       u16* __restrict__ wrb, float* __restrict__ wxT,
                       float* __restrict__ bperm, u16* __restrict__ whb,
                       float* __restrict__ al1, float* __restrict__ be1,
                       float* __restrict__ al2, float* __restrict__ be2,
                       float* __restrict__ alr, float* __restrict__ ber)
{
  int tid = blockIdx.x * blockDim.x + threadIdx.x;
  int nth = gridDim.x * blockDim.x;
  // w1b[o*448 + kt*64 + c] = bf16(w1[o][c][kt])
  for (int idx = tid; idx < 128 * 448; idx += nth) {
    int o = idx / 448, k = idx % 448;
    int kt = k >> 6, c = k & 63;
    w1b[idx] = f2bf(w1[(o * 64 + c) * 7 + kt]);
  }
  // w2b[o*384 + kk*128 + c] = bf16(w2[o][c][kk])
  for (int idx = tid; idx < 96 * 384; idx += nth) {
    int o = idx / 384, k = idx % 384;
    int kk = k >> 7, c = k & 127;
    w2b[idx] = f2bf(w2[(o * 128 + c) * 3 + kk]);
  }
  // wrb[o*128 + c] = bf16(wr[o][c])
  for (int idx = tid; idx < 96 * 128; idx += nth) {
    wrb[idx] = f2bf(wr[idx]);
  }
  // wxT[h*384 + (ch*4+g)] = wx[g*96+ch][h]  (permuted: ch-major gate packing)
  for (int idx = tid; idx < 96 * 384; idx += nth) {
    int c = idx % 384, h = idx / 384;
    int ch = c >> 2, g = c & 3;
    wxT[idx] = wx[((size_t)(g * 96 + ch)) * 96 + h];
  }
  // bperm[ch*4+g] = sbia[g*96+ch]
  for (int c = tid; c < 384; c += nth) {
    int ch = c >> 2, g = c & 3;
    bperm[c] = sbia[g * 96 + ch];
  }
  // whb[row*96 + k] = bf16(wh[(g*96+ch)*96 + k]), row = ch*4+g
  for (int idx = tid; idx < 384 * 96; idx += nth) {
    int row = idx / 96, k = idx % 96;
    int ch = row >> 2, g = row & 3;
    whb[idx] = f2bf(wh[((size_t)(g * 96 + ch)) * 96 + k]);
  }
  for (int o = tid; o < 128; o += nth) {
    float a = g1[o] / sqrtf(v1[o] + 1e-5f);
    al1[o] = a; be1[o] = b1[o] + (cb1[o] - m1[o]) * a;
  }
  for (int o = tid; o < 96; o += nth) {
    float a = g2[o] / sqrtf(v2[o] + 1e-5f);
    al2[o] = a; be2[o] = b2[o] + (cb2[o] - m2[o]) * a;
    float ar = gr[o] / sqrtf(vr[o] + 1e-5f);
    alr[o] = ar; ber[o] = br[o] + (cbr[o] - mr[o]) * ar;
  }
}

// ---------------- K1: conv1 MFMA implicit GEMM (unchanged) ----------------
__launch_bounds__(256, 2)
__global__ void k_conv1(const float* __restrict__ x, const u16* __restrict__ w1b,
                        const float* __restrict__ al1, const float* __restrict__ be1,
                        u16* __restrict__ out1)
{
  __shared__ __align__(16) u16 xs[134 * 72];
  int tid = threadIdx.x;
  int b = blockIdx.y;
  int t0 = blockIdx.x * 128;
  const float* xb = x + (size_t)b * Tt * Cin;

  for (int idx = tid; idx < 134 * 16; idx += 256) {
    int row = idx >> 4, c4 = (idx & 15) << 2;
    int gt = t0 - 3 + row;
    float4 v = make_float4(0.f, 0.f, 0.f, 0.f);
    if (gt >= 0 && gt < Tt) v = *(const float4*)(xb + (size_t)gt * 64 + c4);
    ushort4 s;
    s.x = f2bf(v.x); s.y = f2bf(v.y); s.z = f2bf(v.z); s.w = f2bf(v.w);
    *(ushort4*)(xs + row * 72 + c4) = s;
  }
  __syncthreads();

  int l = tid & 63;
  int wid = tid >> 6;
  int wm = wid >> 1, wn = wid & 1;
  int lr = l & 15, g = l >> 4;

  f32x4 acc[4][4];
#pragma unroll
  for (int i = 0; i < 4; i++)
#pragma unroll
    for (int j = 0; j < 4; j++) acc[i][j] = (f32x4){0.f, 0.f, 0.f, 0.f};

  const u16* wbase = w1b + (size_t)(wn * 64 + lr) * 448;

  for (int s = 0; s < 14; ++s) {
    int kt = s >> 1;
    int cofs = ((s & 1) << 5) + (g << 3);
    const u16* xrow = xs + (wm * 64 + lr + kt) * 72 + cofs;
    bf16x8 a0 = *(const bf16x8*)(xrow);
    bf16x8 a1 = *(const bf16x8*)(xrow + 16 * 72);
    bf16x8 a2 = *(const bf16x8*)(xrow + 32 * 72);
    bf16x8 a3 = *(const bf16x8*)(xrow + 48 * 72);
    int ko = (s << 5) + (g << 3);
    bf16x8 b0 = *(const bf16x8*)(wbase + ko);
    bf16x8 b1 = *(const bf16x8*)(wbase + 16 * 448 + ko);
    bf16x8 b2 = *(const bf16x8*)(wbase + 32 * 448 + ko);
    bf16x8 b3 = *(const bf16x8*)(wbase + 48 * 448 + ko);
    acc[0][0] = MFMA16(a0, b0, acc[0][0]);
    acc[0][1] = MFMA16(a0, b1, acc[0][1]);
    acc[0][2] = MFMA16(a0, b2, acc[0][2]);
    acc[0][3] = MFMA16(a0, b3, acc[0][3]);
    acc[1][0] = MFMA16(a1, b0, acc[1][0]);
    acc[1][1] = MFMA16(a1, b1, acc[1][1]);
    acc[1][2] = MFMA16(a1, b2, acc[1][2]);
    acc[1][3] = MFMA16(a1, b3, acc[1][3]);
    acc[2][0] = MFMA16(a2, b0, acc[2][0]);
    acc[2][1] = MFMA16(a2, b1, acc[2][1]);
    acc[2][2] = MFMA16(a2, b2, acc[2][2]);
    acc[2][3] = MFMA16(a2, b3, acc[2][3]);
    acc[3][0] = MFMA16(a3, b0, acc[3][0]);
    acc[3][1] = MFMA16(a3, b1, acc[3][1]);
    acc[3][2] = MFMA16(a3, b2, acc[3][2]);
    acc[3][3] = MFMA16(a3, b3, acc[3][3]);
  }

  int colb = wn * 64 + lr;
  int rowb = t0 + wm * 64 + (l >> 4) * 4;
#pragma unroll
  for (int nf = 0; nf < 4; nf++) {
    int col = colb + nf * 16;
    float A = al1[col], Bt = be1[col];
#pragma unroll
    for (int mf = 0; mf < 4; mf++) {
      int row = rowb + mf * 16;
#pragma unroll
      for (int r = 0; r < 4; r++) {
        float v = acc[mf][nf][r];
        v = fmaxf(v * A + Bt, 0.f);
        out1[((size_t)b * Tt + row + r) * 128 + col] = f2bf(v);
      }
    }
  }
}

// ---------------- K2: conv2 MFMA implicit GEMM + fused residual (unchanged) ----------------
__launch_bounds__(256, 4)
__global__ void k_conv2(const u16* __restrict__ out1, const u16* __restrict__ w2b,
                        const u16* __restrict__ wrb,
                        const float* __restrict__ al2, const float* __restrict__ be2,
                        const float* __restrict__ alr, const float* __restrict__ ber,
                        float* __restrict__ seq)
{
  int tid = threadIdx.x;
  int b = blockIdx.y;
  int t20 = blockIdx.x * 64;
  int l = tid & 63;
  int wid = tid >> 6;
  int wm = wid >> 1, wn = wid & 1;    // wave tile 32 x 48
  int lr = l & 15, g = l >> 4;

  f32x4 acc[2][3], accr[2][3];
#pragma unroll
  for (int i = 0; i < 2; i++)
#pragma unroll
    for (int j = 0; j < 3; j++) {
      acc[i][j] = (f32x4){0.f, 0.f, 0.f, 0.f};
      accr[i][j] = (f32x4){0.f, 0.f, 0.f, 0.f};
    }

  const u16* ob = out1 + (size_t)b * Tt * 128;
  int colb = wn * 48 + lr;

#pragma unroll
  for (int f = 0; f < 12; f++) {
    int kk = f >> 2;
    int c = ((f & 3) << 5) + (g << 3);
    bf16x8 a[2];
#pragma unroll
    for (int mf = 0; mf < 2; mf++) {
      int t2 = t20 + wm * 32 + mf * 16 + lr;
      int gt = 4 * t2 + kk - 1;
      if (gt >= 0)
        a[mf] = *(const bf16x8*)(ob + (size_t)gt * 128 + c);
      else
        a[mf] = (bf16x8){0, 0, 0, 0, 0, 0, 0, 0};
    }
#pragma unroll
    for (int nf = 0; nf < 3; nf++) {
      int col = colb + nf * 16;
      bf16x8 bb = *(const bf16x8*)(w2b + (size_t)col * 384 + (f << 5) + (g << 3));
      acc[0][nf] = MFMA16(a[0], bb, acc[0][nf]);
      acc[1][nf] = MFMA16(a[1], bb, acc[1][nf]);
    }
    if (kk == 1) {
#pragma unroll
      for (int nf = 0; nf < 3; nf++) {
        int col = colb + nf * 16;
        bf16x8 br = *(const bf16x8*)(wrb + (size_t)col * 128 + ((f & 3) << 5) + (g << 3));
        accr[0][nf] = MFMA16(a[0], br, accr[0][nf]);
        accr[1][nf] = MFMA16(a[1], br, accr[1][nf]);
      }
    }
  }

  int rowb = t20 + wm * 32 + (l >> 4) * 4;
#pragma unroll
  for (int nf = 0; nf < 3; nf++) {
    int col = colb + nf * 16;
    float A = al2[col], Bt = be2[col];
    float Ar = alr[col], Br = ber[col];
#pragma unroll
    for (int mf = 0; mf < 2; mf++) {
      int row = rowb + mf * 16;
#pragma unroll
      for (int r = 0; r < 4; r++) {
        float v = fmaxf(acc[mf][nf][r] * A + Bt, 0.f) + accr[mf][nf][r] * Ar + Br;
        seq[((size_t)b * T2 + row + r) * 96 + col] = v;
      }
    }
  }
}

// ---------------- K3: pre = seq @ wxT + bias, fp32, zero-LDS (unchanged) ----------------
__launch_bounds__(256)
__global__ void k_pre(const float* __restrict__ seq, const float* __restrict__ wxT,
                      const float* __restrict__ bias, float* __restrict__ pre)
{
  int tid = threadIdx.x;
  int b = blockIdx.z, nt = blockIdx.y, t20 = blockIdx.x * 128;
  int g0 = nt * 128;
  int lane32 = tid & 31, col4 = lane32 * 4;
  int trow = (tid >> 5) * 16;

  const float* sb = seq + ((size_t)b * T2 + t20 + trow) * 96;
  const float* wb = wxT + g0 + col4;

  f32x4 acc[16];
#pragma unroll
  for (int r = 0; r < 16; r++) acc[r] = (f32x4){0.f, 0.f, 0.f, 0.f};

  for (int kb = 0; kb < 96; kb += 4) {
    f32x4 bw0 = *(const f32x4*)(wb + (size_t)(kb + 0) * 384);
    f32x4 bw1 = *(const f32x4*)(wb + (size_t)(kb + 1) * 384);
    f32x4 bw2 = *(const f32x4*)(wb + (size_t)(kb + 2) * 384);
    f32x4 bw3 = *(const f32x4*)(wb + (size_t)(kb + 3) * 384);
#pragma unroll
    for (int r = 0; r < 16; r++) {
      f32x4 av = *(const f32x4*)(sb + (size_t)r * 96 + kb);
      acc[r] += av.x * bw0;
      acc[r] += av.y * bw1;
      acc[r] += av.z * bw2;
      acc[r] += av.w * bw3;
    }
  }

  f32x4 b4 = *(const f32x4*)(bias + g0 + col4);
  float* pb = pre + ((size_t)b * T2 + t20 + trow) * 384 + g0 + col4;
#pragma unroll
  for (int r = 0; r < 16; r++) {
    *(f32x4*)(pb + (size_t)r * 384) = acc[r] + b4;
  }
}

// ---------------- K4: sLSTM recurrence v6 — MFMA matvec ----------------
// 256 threads = 4 waves (1/SIMD), one block per batch.
// Per step: preact = whb(bf16,row=ch*4+g) x h(bf16). Wave w owns rows
// [96w, 96w+96) = channels [24w, 24w+24): 6 M-tiles x 3 K-tiles of
// mfma_f32_16x16x32_bf16 (18 MFMA/wave, A-frags preloaded in VGPRs).
// B-frag: h bf16 in LDS; each 16-lane group reads its 8-elem k-slice
// (broadcast) -> every output column equals the matvec; only col 0
// (lanes 0,16,32,48) is written to pwbuf (intra-wave DS FIFO, no barrier).
// Gate lanes (<24) read their channel's float4, add px (prefetch dist 2),
// gate math, write h as bf16 to ping-pong hbuf. One __syncthreads/step.
__launch_bounds__(256, 1)
__global__ void k_slstm(const float* __restrict__ pre, const u16* __restrict__ whb,
                        float* __restrict__ hsum)
{
  __shared__ __align__(16) u16 hbufB[2][96];
  __shared__ __align__(16) float pwbuf[4][96];
  int tid = threadIdx.x;
  int b = blockIdx.x;
  int w = tid >> 6;
  int l = tid & 63;
  int grp = l >> 4, lr = l & 15;

  // A-frags: af[m][kt], row = 96w + 16m + lr, k = kt*32 + grp*8 + reg
  bf16x8 af[6][3];
#pragma unroll
  for (int m = 0; m < 6; m++) {
    const u16* wrow = whb + (size_t)(96 * w + 16 * m + lr) * 96 + grp * 8;
#pragma unroll
    for (int kt = 0; kt < 3; kt++) af[m][kt] = *(const bf16x8*)(wrow + kt * 32);
  }

  bool gl = (l < 24);
  float c = 0.f, n = 0.f, mm = 0.f, hs = 0.f;
  if (tid < 96) hbufB[0][tid] = 0;
  __syncthreads();

  // px prefetch (gate lanes): float4 (z,i,f,o) for ch = 24w + l
  const float4* pxp = (const float4*)(pre + (size_t)b * T2 * G4) + (24 * w + l);
  float4 pxA = make_float4(0, 0, 0, 0), pxB = pxA;
  if (gl) { pxA = pxp[0]; pxB = pxp[96]; }

  const float L2E = 1.44269504f;
  const f32x4 zero4 = {0.f, 0.f, 0.f, 0.f};
  int p = 0;
  for (int t = 0; t < T2; t++) {
    float4 pxN = make_float4(0, 0, 0, 0);
    if (gl) {
      int tn = t + 2 < T2 ? t + 2 : T2 - 1;
      pxN = pxp[(size_t)tn * 96];
    }
    // B-frags: group g reads h[kt*32 + g*8 .. +8] as bf16x8 (broadcast)
    const u16* hb = hbufB[p] + grp * 8;
    bf16x8 b0 = *(const bf16x8*)(hb);
    bf16x8 b1 = *(const bf16x8*)(hb + 32);
    bf16x8 b2 = *(const bf16x8*)(hb + 64);

    f32x4 acc[6];
#pragma unroll
    for (int m = 0; m < 6; m++) {
      f32x4 a = MFMA16(af[m][0], b0, zero4);
      a = MFMA16(af[m][1], b1, a);
      acc[m] = MFMA16(af[m][2], b2, a);
    }
    // col 0 lanes publish rows (intra-wave FIFO; gate lanes read own wave's rows)
    if (lr == 0) {
#pragma unroll
      for (int m = 0; m < 6; m++)
        *(f32x4*)(&pwbuf[w][16 * m + grp * 4]) = acc[m];
    }
    asm volatile("" ::: "memory");
    if (gl) {
      f32x4 pa = *(const f32x4*)(&pwbuf[w][4 * l]);
      float zp = pa[0] + pxA.x, ip = pa[1] + pxA.y;
      float fp = pa[2] + pxA.z, op = pa[3] + pxA.w;
      float zc = fminf(fmaxf(zp, -30.f), 30.f);
      float ez = exp2f(zc * (2.f * L2E));
      float z = 1.f - 2.f * __builtin_amdgcn_rcpf(ez + 1.f);
      float oc = fminf(fmaxf(op, -30.f), 30.f);
      float o = __builtin_amdgcn_rcpf(1.f + exp2f(-oc * L2E));
      float mn = fmaxf(fp + mm, ip);
      float iv = exp2f((ip - mn) * L2E);
      float fv = exp2f((fp + mm - mn) * L2E);
      c = fv * c + iv * z;
      n = fv * n + iv;
      mm = mn;
      float h = o * c * __builtin_amdgcn_rcpf(fmaxf(n, 1.f));
      hs += h;
      hbufB[p ^ 1][24 * w + l] = f2bf(h);
    }
    pxA = pxB; pxB = pxN;
    __syncthreads();
    p ^= 1;
  }
  if (gl) hsum[b * 96 + 24 * w + l] = hs * (1.f / 1024.f);
}

// ---------------- K5: head (unchanged) ----------------
__launch_bounds__(128)
__global__ void k_head(const float* __restrict__ hsum, const float* __restrict__ fc1w,
                       const float* __restrict__ fc1b, const float* __restrict__ fc2w,
                       const float* __restrict__ fc2b, float* __restrict__ out)
{
  __shared__ float p[96];
  __shared__ float z1[128];
  int tid = threadIdx.x, b = blockIdx.x;
  if (tid < 96) p[tid] = hsum[b * 96 + tid];
  __syncthreads();
  {
    float a = fc1b[tid];
    const float* wr = fc1w + tid * 96;
    for (int h = 0; h < 96; h++) a += p[h] * wr[h];
    z1[tid] = fmaxf(a, 0.f);
  }
  __syncthreads();
  if (tid < NC) {
    float a = fc2b[tid];
    const float* wr = fc2w + tid * 128;
    for (int j = 0; j < 128; j++) a += z1[j] * wr[j];
    out[b * NC + tid] = a;
  }
}

extern "C" void kernel_launch(void* const* d_in, const int* in_sizes, int n_in,
                              void* d_out, int out_size, void* d_ws, size_t ws_size,
                              hipStream_t stream)
{
  const float* x    = (const float*)d_in[0];
  const float* w1   = (const float*)d_in[1];
  const float* cb1  = (const float*)d_in[2];
  const float* g1   = (const float*)d_in[3];
  const float* b1   = (const float*)d_in[4];
  const float* m1   = (const float*)d_in[5];
  const float* v1   = (const float*)d_in[6];
  const float* w2   = (const float*)d_in[7];
  const float* cb2  = (const float*)d_in[8];
  const float* g2   = (const float*)d_in[9];
  const float* b2   = (const float*)d_in[10];
  const float* m2   = (const float*)d_in[11];
  const float* v2   = (const float*)d_in[12];
  const float* wr   = (const float*)d_in[13];
  const float* cbr  = (const float*)d_in[14];
  const float* gr   = (const float*)d_in[15];
  const float* br   = (const float*)d_in[16];
  const float* mr   = (const float*)d_in[17];
  const float* vr   = (const float*)d_in[18];
  const float* wx   = (const float*)d_in[19];
  const float* wh   = (const float*)d_in[20];
  const float* sbia = (const float*)d_in[21];
  const float* fc1w = (const float*)d_in[22];
  const float* fc1b = (const float*)d_in[23];
  const float* fc2w = (const float*)d_in[24];
  const float* fc2b = (const float*)d_in[25];

  char* ws = (char*)d_ws;
  size_t off = 0;
  auto alloc = [&](size_t bytes) -> void* {
    void* p = (void*)(ws + off);
    off = (off + bytes + 255) & ~((size_t)255);
    return p;
  };
  u16*   out1 = (u16*)  alloc((size_t)Bz * Tt * K1c * 2);   // 67.1 MB
  float* seq  = (float*)alloc((size_t)Bz * T2 * Hh * 4);    // 25.2 MB
  float* pre  = (float*)alloc((size_t)Bz * T2 * G4 * 4);    // 100.7 MB
  u16*   w1b  = (u16*)  alloc(448 * 128 * 2);
  u16*   w2b  = (u16*)  alloc(96 * 384 * 2);
  u16*   wrb  = (u16*)  alloc(96 * 128 * 2);
  float* wxT  = (float*)alloc(96 * 384 * 4);
  float* bperm= (float*)alloc(384 * 4);
  u16*   whb  = (u16*)  alloc(384 * 96 * 2);
  float* al1  = (float*)alloc(128 * 4);
  float* be1  = (float*)alloc(128 * 4);
  float* al2  = (float*)alloc(96 * 4);
  float* be2  = (float*)alloc(96 * 4);
  float* alr  = (float*)alloc(96 * 4);
  float* ber  = (float*)alloc(96 * 4);
  float* hsum = (float*)alloc((size_t)Bz * Hh * 4);
  (void)ws_size; (void)in_sizes; (void)n_in; (void)out_size;

  k_prep<<<dim3(224), dim3(256), 0, stream>>>(
      w1, cb1, g1, b1, m1, v1, w2, cb2, g2, b2, m2, v2,
      wr, cbr, gr, br, mr, vr, wx, sbia, wh,
      w1b, w2b, wrb, wxT, bperm, whb, al1, be1, al2, be2, alr, ber);

  k_conv1<<<dim3(Tt / 128, Bz), dim3(256), 0, stream>>>(x, w1b, al1, be1, out1);

  k_conv2<<<dim3(T2 / 64, Bz), dim3(256), 0, stream>>>(out1, w2b, wrb, al2, be2, alr, ber, seq);

  k_pre<<<dim3(T2 / 128, 3, Bz), dim3(256), 0, stream>>>(seq, wxT, bperm, pre);

  k_slstm<<<dim3(Bz), dim3(256), 0, stream>>>(pre, whb, hsum);

  k_head<<<dim3(Bz), dim3(128), 0, stream>>>(hsum, fc1w, fc1b, fc2w, fc2b, (float*)d_out);
}

// Round 10
// 786.722 us; speedup vs baseline: 1.3709x; 1.0508x over previous
//
#include <hip/hip_runtime.h>
#include <hip/hip_bf16.h>
#include <math.h>

typedef unsigned short u16;
typedef short bf16x8 __attribute__((ext_vector_type(8)));
typedef float f32x4 __attribute__((ext_vector_type(4)));

#define Bz 64
#define Tt 4096
#define Cin 64
#define K1c 128
#define Hh 96
#define T2 1024
#define G4 384
#define NC 109

#define MFMA16(a, b, c) __builtin_amdgcn_mfma_f32_16x16x32_bf16(a, b, c, 0, 0, 0)

__device__ __forceinline__ float bf2f(u16 v) {
  union { unsigned int u; float f; } x; x.u = ((unsigned int)v) << 16; return x.f;
}
__device__ __forceinline__ u16 f2bf(float f) {
  union { unsigned int u; float f; } x; x.f = f;
  unsigned int u = x.u;
  unsigned int r = u + 0x7fff + ((u >> 16) & 1);
  return (u16)(r >> 16);
}

// Gate scale: z-gate rows carry 2*log2(e), i/f/o rows carry log2(e).
// Folded into whb, wxT, bperm at prep time; sLSTM gate math then uses raw exp2.
__device__ __forceinline__ float gate_scale(int g) {
  const float L2E = 1.44269504f;
  return (g == 0) ? 2.f * L2E : L2E;
}

// ---------------- K0: weight packing + BN folding ----------------
__global__ void k_prep(const float* __restrict__ w1, const float* __restrict__ cb1,
                       const float* __restrict__ g1, const float* __restrict__ b1,
                       const float* __restrict__ m1, const float* __restrict__ v1,
                       const float* __restrict__ w2, const float* __restrict__ cb2,
                       const float* __restrict__ g2, const float* __restrict__ b2,
                       const float* __restrict__ m2, const float* __restrict__ v2,
                       const float* __restrict__ wr, const float* __restrict__ cbr,
                       const float* __restrict__ gr, const float* __restrict__ br,
                       const float* __restrict__ mr, const float* __restrict__ vr,
                       const float* __restrict__ wx, const float* __restrict__ sbia,
                       const float* __restrict__ wh,
                       u16* __restrict__ w1b, u16* __restrict__ w2b,
                       u16* __restrict__ wrb, float* __restrict__ wxT,
                       float* __restrict__ bperm, u16* __restrict__ whb,
                       float* __restrict__ al1, float* __restrict__ be1,
                       float* __restrict__ al2, float* __restrict__ be2,
                       float* __restrict__ alr, float* __restrict__ ber)
{
  int tid = blockIdx.x * blockDim.x + threadIdx.x;
  int nth = gridDim.x * blockDim.x;
  // w1b[o*448 + kt*64 + c] = bf16(w1[o][c][kt])
  for (int idx = tid; idx < 128 * 448; idx += nth) {
    int o = idx / 448, k = idx % 448;
    int kt = k >> 6, c = k & 63;
    w1b[idx] = f2bf(w1[(o * 64 + c) * 7 + kt]);
  }
  // w2b[o*384 + kk*128 + c] = bf16(w2[o][c][kk])
  for (int idx = tid; idx < 96 * 384; idx += nth) {
    int o = idx / 384, k = idx % 384;
    int kk = k >> 7, c = k & 127;
    w2b[idx] = f2bf(w2[(o * 128 + c) * 3 + kk]);
  }
  // wrb[o*128 + c] = bf16(wr[o][c])
  for (int idx = tid; idx < 96 * 128; idx += nth) {
    wrb[idx] = f2bf(wr[idx]);
  }
  // wxT[h*384 + (ch*4+g)] = wx[g*96+ch][h] * gate_scale(g)
  for (int idx = tid; idx < 96 * 384; idx += nth) {
    int c = idx % 384, h = idx / 384;
    int ch = c >> 2, g = c & 3;
    wxT[idx] = wx[((size_t)(g * 96 + ch)) * 96 + h] * gate_scale(g);
  }
  // bperm[ch*4+g] = sbia[g*96+ch] * gate_scale(g)
  for (int c = tid; c < 384; c += nth) {
    int ch = c >> 2, g = c & 3;
    bperm[c] = sbia[g * 96 + ch] * gate_scale(g);
  }
  // whb[row*96 + k] = bf16(wh[(g*96+ch)*96 + k] * gate_scale(g)), row = ch*4+g
  for (int idx = tid; idx < 384 * 96; idx += nth) {
    int row = idx / 96, k = idx % 96;
    int ch = row >> 2, g = row & 3;
    whb[idx] = f2bf(wh[((size_t)(g * 96 + ch)) * 96 + k] * gate_scale(g));
  }
  for (int o = tid; o < 128; o += nth) {
    float a = g1[o] / sqrtf(v1[o] + 1e-5f);
    al1[o] = a; be1[o] = b1[o] + (cb1[o] - m1[o]) * a;
  }
  for (int o = tid; o < 96; o += nth) {
    float a = g2[o] / sqrtf(v2[o] + 1e-5f);
    al2[o] = a; be2[o] = b2[o] + (cb2[o] - m2[o]) * a;
    float ar = gr[o] / sqrtf(vr[o] + 1e-5f);
    alr[o] = ar; ber[o] = br[o] + (cbr[o] - mr[o]) * ar;
  }
}

// ---------------- K1: conv1 MFMA implicit GEMM (unchanged) ----------------
__launch_bounds__(256, 2)
__global__ void k_conv1(const float* __restrict__ x, const u16* __restrict__ w1b,
                        const float* __restrict__ al1, const float* __restrict__ be1,
                        u16* __restrict__ out1)
{
  __shared__ __align__(16) u16 xs[134 * 72];
  int tid = threadIdx.x;
  int b = blockIdx.y;
  int t0 = blockIdx.x * 128;
  const float* xb = x + (size_t)b * Tt * Cin;

  for (int idx = tid; idx < 134 * 16; idx += 256) {
    int row = idx >> 4, c4 = (idx & 15) << 2;
    int gt = t0 - 3 + row;
    float4 v = make_float4(0.f, 0.f, 0.f, 0.f);
    if (gt >= 0 && gt < Tt) v = *(const float4*)(xb + (size_t)gt * 64 + c4);
    ushort4 s;
    s.x = f2bf(v.x); s.y = f2bf(v.y); s.z = f2bf(v.z); s.w = f2bf(v.w);
    *(ushort4*)(xs + row * 72 + c4) = s;
  }
  __syncthreads();

  int l = tid & 63;
  int wid = tid >> 6;
  int wm = wid >> 1, wn = wid & 1;
  int lr = l & 15, g = l >> 4;

  f32x4 acc[4][4];
#pragma unroll
  for (int i = 0; i < 4; i++)
#pragma unroll
    for (int j = 0; j < 4; j++) acc[i][j] = (f32x4){0.f, 0.f, 0.f, 0.f};

  const u16* wbase = w1b + (size_t)(wn * 64 + lr) * 448;

  for (int s = 0; s < 14; ++s) {
    int kt = s >> 1;
    int cofs = ((s & 1) << 5) + (g << 3);
    const u16* xrow = xs + (wm * 64 + lr + kt) * 72 + cofs;
    bf16x8 a0 = *(const bf16x8*)(xrow);
    bf16x8 a1 = *(const bf16x8*)(xrow + 16 * 72);
    bf16x8 a2 = *(const bf16x8*)(xrow + 32 * 72);
    bf16x8 a3 = *(const bf16x8*)(xrow + 48 * 72);
    int ko = (s << 5) + (g << 3);
    bf16x8 b0 = *(const bf16x8*)(wbase + ko);
    bf16x8 b1 = *(const bf16x8*)(wbase + 16 * 448 + ko);
    bf16x8 b2 = *(const bf16x8*)(wbase + 32 * 448 + ko);
    bf16x8 b3 = *(const bf16x8*)(wbase + 48 * 448 + ko);
    acc[0][0] = MFMA16(a0, b0, acc[0][0]);
    acc[0][1] = MFMA16(a0, b1, acc[0][1]);
    acc[0][2] = MFMA16(a0, b2, acc[0][2]);
    acc[0][3] = MFMA16(a0, b3, acc[0][3]);
    acc[1][0] = MFMA16(a1, b0, acc[1][0]);
    acc[1][1] = MFMA16(a1, b1, acc[1][1]);
    acc[1][2] = MFMA16(a1, b2, acc[1][2]);
    acc[1][3] = MFMA16(a1, b3, acc[1][3]);
    acc[2][0] = MFMA16(a2, b0, acc[2][0]);
    acc[2][1] = MFMA16(a2, b1, acc[2][1]);
    acc[2][2] = MFMA16(a2, b2, acc[2][2]);
    acc[2][3] = MFMA16(a2, b3, acc[2][3]);
    acc[3][0] = MFMA16(a3, b0, acc[3][0]);
    acc[3][1] = MFMA16(a3, b1, acc[3][1]);
    acc[3][2] = MFMA16(a3, b2, acc[3][2]);
    acc[3][3] = MFMA16(a3, b3, acc[3][3]);
  }

  int colb = wn * 64 + lr;
  int rowb = t0 + wm * 64 + (l >> 4) * 4;
#pragma unroll
  for (int nf = 0; nf < 4; nf++) {
    int col = colb + nf * 16;
    float A = al1[col], Bt = be1[col];
#pragma unroll
    for (int mf = 0; mf < 4; mf++) {
      int row = rowb + mf * 16;
#pragma unroll
      for (int r = 0; r < 4; r++) {
        float v = acc[mf][nf][r];
        v = fmaxf(v * A + Bt, 0.f);
        out1[((size_t)b * Tt + row + r) * 128 + col] = f2bf(v);
      }
    }
  }
}

// ---------------- K2: conv2 MFMA implicit GEMM + fused residual (unchanged) ----------------
__launch_bounds__(256, 4)
__global__ void k_conv2(const u16* __restrict__ out1, const u16* __restrict__ w2b,
                        const u16* __restrict__ wrb,
                        const float* __restrict__ al2, const float* __restrict__ be2,
                        const float* __restrict__ alr, const float* __restrict__ ber,
                        float* __restrict__ seq)
{
  int tid = threadIdx.x;
  int b = blockIdx.y;
  int t20 = blockIdx.x * 64;
  int l = tid & 63;
  int wid = tid >> 6;
  int wm = wid >> 1, wn = wid & 1;    // wave tile 32 x 48
  int lr = l & 15, g = l >> 4;

  f32x4 acc[2][3], accr[2][3];
#pragma unroll
  for (int i = 0; i < 2; i++)
#pragma unroll
    for (int j = 0; j < 3; j++) {
      acc[i][j] = (f32x4){0.f, 0.f, 0.f, 0.f};
      accr[i][j] = (f32x4){0.f, 0.f, 0.f, 0.f};
    }

  const u16* ob = out1 + (size_t)b * Tt * 128;
  int colb = wn * 48 + lr;

#pragma unroll
  for (int f = 0; f < 12; f++) {
    int kk = f >> 2;
    int c = ((f & 3) << 5) + (g << 3);
    bf16x8 a[2];
#pragma unroll
    for (int mf = 0; mf < 2; mf++) {
      int t2 = t20 + wm * 32 + mf * 16 + lr;
      int gt = 4 * t2 + kk - 1;
      if (gt >= 0)
        a[mf] = *(const bf16x8*)(ob + (size_t)gt * 128 + c);
      else
        a[mf] = (bf16x8){0, 0, 0, 0, 0, 0, 0, 0};
    }
#pragma unroll
    for (int nf = 0; nf < 3; nf++) {
      int col = colb + nf * 16;
      bf16x8 bb = *(const bf16x8*)(w2b + (size_t)col * 384 + (f << 5) + (g << 3));
      acc[0][nf] = MFMA16(a[0], bb, acc[0][nf]);
      acc[1][nf] = MFMA16(a[1], bb, acc[1][nf]);
    }
    if (kk == 1) {
#pragma unroll
      for (int nf = 0; nf < 3; nf++) {
        int col = colb + nf * 16;
        bf16x8 br = *(const bf16x8*)(wrb + (size_t)col * 128 + ((f & 3) << 5) + (g << 3));
        accr[0][nf] = MFMA16(a[0], br, accr[0][nf]);
        accr[1][nf] = MFMA16(a[1], br, accr[1][nf]);
      }
    }
  }

  int rowb = t20 + wm * 32 + (l >> 4) * 4;
#pragma unroll
  for (int nf = 0; nf < 3; nf++) {
    int col = colb + nf * 16;
    float A = al2[col], Bt = be2[col];
    float Ar = alr[col], Br = ber[col];
#pragma unroll
    for (int mf = 0; mf < 2; mf++) {
      int row = rowb + mf * 16;
#pragma unroll
      for (int r = 0; r < 4; r++) {
        float v = fmaxf(acc[mf][nf][r] * A + Bt, 0.f) + accr[mf][nf][r] * Ar + Br;
        seq[((size_t)b * T2 + row + r) * 96 + col] = v;
      }
    }
  }
}

// ---------------- K3: pre = seq @ wxT + bias, fp32, zero-LDS (unchanged) ----------------
__launch_bounds__(256)
__global__ void k_pre(const float* __restrict__ seq, const float* __restrict__ wxT,
                      const float* __restrict__ bias, float* __restrict__ pre)
{
  int tid = threadIdx.x;
  int b = blockIdx.z, nt = blockIdx.y, t20 = blockIdx.x * 128;
  int g0 = nt * 128;
  int lane32 = tid & 31, col4 = lane32 * 4;
  int trow = (tid >> 5) * 16;

  const float* sb = seq + ((size_t)b * T2 + t20 + trow) * 96;
  const float* wb = wxT + g0 + col4;

  f32x4 acc[16];
#pragma unroll
  for (int r = 0; r < 16; r++) acc[r] = (f32x4){0.f, 0.f, 0.f, 0.f};

  for (int kb = 0; kb < 96; kb += 4) {
    f32x4 bw0 = *(const f32x4*)(wb + (size_t)(kb + 0) * 384);
    f32x4 bw1 = *(const f32x4*)(wb + (size_t)(kb + 1) * 384);
    f32x4 bw2 = *(const f32x4*)(wb + (size_t)(kb + 2) * 384);
    f32x4 bw3 = *(const f32x4*)(wb + (size_t)(kb + 3) * 384);
#pragma unroll
    for (int r = 0; r < 16; r++) {
      f32x4 av = *(const f32x4*)(sb + (size_t)r * 96 + kb);
      acc[r] += av.x * bw0;
      acc[r] += av.y * bw1;
      acc[r] += av.z * bw2;
      acc[r] += av.w * bw3;
    }
  }

  f32x4 b4 = *(const f32x4*)(bias + g0 + col4);
  float* pb = pre + ((size_t)b * T2 + t20 + trow) * 384 + g0 + col4;
#pragma unroll
  for (int r = 0; r < 16; r++) {
    *(f32x4*)(pb + (size_t)r * 384) = acc[r] + b4;
  }
}

// ---------------- K4: sLSTM recurrence v7 — MFMA matvec, in-lane gates ----------------
// 256 threads = 4 waves (1/SIMD), one block per batch.
// MFMA C-layout insight: lane (grp=l>>4, lr=l&15) holds acc[m][reg] =
// preact row 16m+4grp+reg, i.e. ALL FOUR gates of channel 4m+grp (m=0..5),
// replicated over lr. So lane (grp, lr<6) owns channel ch=24w+4lr+grp:
// select acc[lr] via a 5-op cndmask tree (no LDS round-trip), add px
// (prefetched dist 2), gate math (exp2-domain, scales folded into weights),
// write h bf16 to ping-pong hbuf. One __syncthreads per step.
__launch_bounds__(256, 1)
__global__ void k_slstm(const float* __restrict__ pre, const u16* __restrict__ whb,
                        float* __restrict__ hsum)
{
  __shared__ __align__(16) u16 hbufB[2][96];
  int tid = threadIdx.x;
  int b = blockIdx.x;
  int w = tid >> 6;
  int l = tid & 63;
  int grp = l >> 4, lr = l & 15;

  // A-frags: af[m][kt], row = 96w + 16m + lr, k = kt*32 + grp*8 + reg
  bf16x8 af[6][3];
#pragma unroll
  for (int m = 0; m < 6; m++) {
    const u16* wrow = whb + (size_t)(96 * w + 16 * m + lr) * 96 + grp * 8;
#pragma unroll
    for (int kt = 0; kt < 3; kt++) af[m][kt] = *(const bf16x8*)(wrow + kt * 32);
  }

  bool gl = (lr < 6);
  int ch = 24 * w + 4 * lr + grp;   // valid when gl
  float c = 0.f, n = 0.f, mm = 0.f, hs = 0.f;
  if (tid < 96) hbufB[0][tid] = 0;
  __syncthreads();

  // px prefetch: float4 (z,i,f,o) for this lane's channel
  const float4* pxp = (const float4*)(pre + (size_t)b * T2 * G4) + (gl ? ch : 0);
  float4 pxA = make_float4(0, 0, 0, 0), pxB = pxA;
  if (gl) { pxA = pxp[0]; pxB = pxp[96]; }

  const f32x4 zero4 = {0.f, 0.f, 0.f, 0.f};
  int p = 0;
  for (int t = 0; t < T2; t++) {
    float4 pxN = make_float4(0, 0, 0, 0);
    if (gl) {
      int tn = t + 2 < T2 ? t + 2 : T2 - 1;
      pxN = pxp[(size_t)tn * 96];
    }
    // B-frags: group g reads h[kt*32 + g*8 .. +8] as bf16x8 (broadcast)
    const u16* hb = hbufB[p] + grp * 8;
    bf16x8 b0 = *(const bf16x8*)(hb);
    bf16x8 b1 = *(const bf16x8*)(hb + 32);
    bf16x8 b2 = *(const bf16x8*)(hb + 64);

    f32x4 acc[6];
#pragma unroll
    for (int m = 0; m < 6; m++) {
      f32x4 aP = MFMA16(af[m][0], b0, zero4);
      f32x4 aQ = MFMA16(af[m][1], b1, zero4);
      aP = MFMA16(af[m][2], b2, aP);
      acc[m] = aP + aQ;
    }
    // select acc[lr] (lr<6) via cndmask tree
    f32x4 x01 = (lr & 1) ? acc[1] : acc[0];
    f32x4 x23 = (lr & 1) ? acc[3] : acc[2];
    f32x4 x45 = (lr & 1) ? acc[5] : acc[4];
    f32x4 y0 = (lr & 2) ? x23 : x01;
    f32x4 pa = (lr & 4) ? x45 : y0;

    if (gl) {
      float zp = pa[0] + pxA.x, ip = pa[1] + pxA.y;
      float fp = pa[2] + pxA.z, op = pa[3] + pxA.w;
      // all preacts pre-scaled: z by 2*log2e, i/f/o by log2e
      float zc = fminf(fmaxf(zp, -86.f), 86.f);
      float ez = exp2f(zc);
      float z = 1.f - 2.f * __builtin_amdgcn_rcpf(ez + 1.f);
      float oc = fminf(fmaxf(op, -60.f), 60.f);
      float o = __builtin_amdgcn_rcpf(1.f + exp2f(-oc));
      float mn = fmaxf(fp + mm, ip);
      float iv = exp2f(ip - mn);
      float fv = exp2f(fp + mm - mn);
      c = fv * c + iv * z;
      n = fv * n + iv;
      mm = mn;
      float h = o * c * __builtin_amdgcn_rcpf(fmaxf(n, 1.f));
      hs += h;
      hbufB[p ^ 1][ch] = f2bf(h);
    }
    pxA = pxB; pxB = pxN;
    __syncthreads();
    p ^= 1;
  }
  if (gl) hsum[b * 96 + ch] = hs * (1.f / 1024.f);
}

// ---------------- K5: head (unchanged) ----------------
__launch_bounds__(128)
__global__ void k_head(const float* __restrict__ hsum, const float* __restrict__ fc1w,
                       const float* __restrict__ fc1b, const float* __restrict__ fc2w,
                       const float* __restrict__ fc2b, float* __restrict__ out)
{
  __shared__ float p[96];
  __shared__ float z1[128];
  int tid = threadIdx.x, b = blockIdx.x;
  if (tid < 96) p[tid] = hsum[b * 96 + tid];
  __syncthreads();
  {
    float a = fc1b[tid];
    const float* wr = fc1w + tid * 96;
    for (int h = 0; h < 96; h++) a += p[h] * wr[h];
    z1[tid] = fmaxf(a, 0.f);
  }
  __syncthreads();
  if (tid < NC) {
    float a = fc2b[tid];
    const float* wr = fc2w + tid * 128;
    for (int j = 0; j < 128; j++) a += z1[j] * wr[j];
    out[b * NC + tid] = a;
  }
}

extern "C" void kernel_launch(void* const* d_in, const int* in_sizes, int n_in,
                              void* d_out, int out_size, void* d_ws, size_t ws_size,
                              hipStream_t stream)
{
  const float* x    = (const float*)d_in[0];
  const float* w1   = (const float*)d_in[1];
  const float* cb1  = (const float*)d_in[2];
  const float* g1   = (const float*)d_in[3];
  const float* b1   = (const float*)d_in[4];
  const float* m1   = (const float*)d_in[5];
  const float* v1   = (const float*)d_in[6];
  const float* w2   = (const float*)d_in[7];
  const float* cb2  = (const float*)d_in[8];
  const float* g2   = (const float*)d_in[9];
  const float* b2   = (const float*)d_in[10];
  const float* m2   = (const float*)d_in[11];
  const float* v2   = (const float*)d_in[12];
  const float* wr   = (const float*)d_in[13];
  const float* cbr  = (const float*)d_in[14];
  const float* gr   = (const float*)d_in[15];
  const float* br   = (const float*)d_in[16];
  const float* mr   = (const float*)d_in[17];
  const float* vr   = (const float*)d_in[18];
  const float* wx   = (const float*)d_in[19];
  const float* wh   = (const float*)d_in[20];
  const float* sbia = (const float*)d_in[21];
  const float* fc1w = (const float*)d_in[22];
  const float* fc1b = (const float*)d_in[23];
  const float* fc2w = (const float*)d_in[24];
  const float* fc2b = (const float*)d_in[25];

  char* ws = (char*)d_ws;
  size_t off = 0;
  auto alloc = [&](size_t bytes) -> void* {
    void* p = (void*)(ws + off);
    off = (off + bytes + 255) & ~((size_t)255);
    return p;
  };
  u16*   out1 = (u16*)  alloc((size_t)Bz * Tt * K1c * 2);   // 67.1 MB
  float* seq  = (float*)alloc((size_t)Bz * T2 * Hh * 4);    // 25.2 MB
  float* pre  = (float*)alloc((size_t)Bz * T2 * G4 * 4);    // 100.7 MB
  u16*   w1b  = (u16*)  alloc(448 * 128 * 2);
  u16*   w2b  = (u16*)  alloc(96 * 384 * 2);
  u16*   wrb  = (u16*)  alloc(96 * 128 * 2);
  float* wxT  = (float*)alloc(96 * 384 * 4);
  float* bperm= (float*)alloc(384 * 4);
  u16*   whb  = (u16*)  alloc(384 * 96 * 2);
  float* al1  = (float*)alloc(128 * 4);
  float* be1  = (float*)alloc(128 * 4);
  float* al2  = (float*)alloc(96 * 4);
  float* be2  = (float*)alloc(96 * 4);
  float* alr  = (float*)alloc(96 * 4);
  float* ber  = (float*)alloc(96 * 4);
  float* hsum = (float*)alloc((size_t)Bz * Hh * 4);
  (void)ws_size; (void)in_sizes; (void)n_in; (void)out_size;

  k_prep<<<dim3(224), dim3(256), 0, stream>>>(
      w1, cb1, g1, b1, m1, v1, w2, cb2, g2, b2, m2, v2,
      wr, cbr, gr, br, mr, vr, wx, sbia, wh,
      w1b, w2b, wrb, wxT, bperm, whb, al1, be1, al2, be2, alr, ber);

  k_conv1<<<dim3(Tt / 128, Bz), dim3(256), 0, stream>>>(x, w1b, al1, be1, out1);

  k_conv2<<<dim3(T2 / 64, Bz), dim3(256), 0, stream>>>(out1, w2b, wrb, al2, be2, alr, ber, seq);

  k_pre<<<dim3(T2 / 128, 3, Bz), dim3(256), 0, stream>>>(seq, wxT, bperm, pre);

  k_slstm<<<dim3(Bz), dim3(256), 0, stream>>>(pre, whb, hsum);

  k_head<<<dim3(Bz), dim3(128), 0, stream>>>(hsum, fc1w, fc1b, fc2w, fc2b, (float*)d_out);
}

// Round 11
// 719.373 us; speedup vs baseline: 1.4993x; 1.0936x over previous
//
#include <hip/hip_runtime.h>
#include <hip/hip_bf16.h>
#include <math.h>

typedef unsigned short u16;
typedef short bf16x8 __attribute__((ext_vector_type(8)));
typedef float f32x4 __attribute__((ext_vector_type(4)));

#define Bz 64
#define Tt 4096
#define Cin 64
#define K1c 128
#define Hh 96
#define T2 1024
#define G4 384
#define NC 109

#define MFMA16(a, b, c) __builtin_amdgcn_mfma_f32_16x16x32_bf16(a, b, c, 0, 0, 0)

__device__ __forceinline__ float bf2f(u16 v) {
  union { unsigned int u; float f; } x; x.u = ((unsigned int)v) << 16; return x.f;
}
__device__ __forceinline__ u16 f2bf(float f) {
  union { unsigned int u; float f; } x; x.f = f;
  unsigned int u = x.u;
  unsigned int r = u + 0x7fff + ((u >> 16) & 1);
  return (u16)(r >> 16);
}

// Gate scale: z-gate rows carry 2*log2(e), i/f/o rows carry log2(e).
// Folded into whb, wxb, bperm at prep time; sLSTM gate math then uses raw exp2.
__device__ __forceinline__ float gate_scale(int g) {
  const float L2E = 1.44269504f;
  return (g == 0) ? 2.f * L2E : L2E;
}

// ---------------- K0: weight packing + BN folding ----------------
__global__ void k_prep(const float* __restrict__ w1, const float* __restrict__ cb1,
                       const float* __restrict__ g1, const float* __restrict__ b1,
                       const float* __restrict__ m1, const float* __restrict__ v1,
                       const float* __restrict__ w2, const float* __restrict__ cb2,
                       const float* __restrict__ g2, const float* __restrict__ b2,
                       const float* __restrict__ m2, const float* __restrict__ v2,
                       const float* __restrict__ wr, const float* __restrict__ cbr,
                       const float* __restrict__ gr, const float* __restrict__ br,
                       const float* __restrict__ mr, const float* __restrict__ vr,
                       const float* __restrict__ wx, const float* __restrict__ sbia,
                       const float* __restrict__ wh,
                       u16* __restrict__ w1b, u16* __restrict__ w2b,
                       u16* __restrict__ wrb, u16* __restrict__ wxb,
                       float* __restrict__ bperm, u16* __restrict__ whb,
                       float* __restrict__ al1, float* __restrict__ be1,
                       float* __restrict__ al2, float* __restrict__ be2,
                       float* __restrict__ alr, float* __restrict__ ber)
{
  int tid = blockIdx.x * blockDim.x + threadIdx.x;
  int nth = gridDim.x * blockDim.x;
  // w1b[o*448 + kt*64 + c] = bf16(w1[o][c][kt])
  for (int idx = tid; idx < 128 * 448; idx += nth) {
    int o = idx / 448, k = idx % 448;
    int kt = k >> 6, c = k & 63;
    w1b[idx] = f2bf(w1[(o * 64 + c) * 7 + kt]);
  }
  // w2b[o*384 + kk*128 + c] = bf16(w2[o][c][kk])
  for (int idx = tid; idx < 96 * 384; idx += nth) {
    int o = idx / 384, k = idx % 384;
    int kk = k >> 7, c = k & 127;
    w2b[idx] = f2bf(w2[(o * 128 + c) * 3 + kk]);
  }
  // wrb[o*128 + c] = bf16(wr[o][c])
  for (int idx = tid; idx < 96 * 128; idx += nth) {
    wrb[idx] = f2bf(wr[idx]);
  }
  // wxb[row*96 + k] = bf16(wx[(g*96+ch)*96 + k] * gate_scale(g)), row = ch*4+g
  for (int idx = tid; idx < 384 * 96; idx += nth) {
    int row = idx / 96, k = idx % 96;
    int ch = row >> 2, g = row & 3;
    wxb[idx] = f2bf(wx[((size_t)(g * 96 + ch)) * 96 + k] * gate_scale(g));
  }
  // bperm[ch*4+g] = sbia[g*96+ch] * gate_scale(g)
  for (int c = tid; c < 384; c += nth) {
    int ch = c >> 2, g = c & 3;
    bperm[c] = sbia[g * 96 + ch] * gate_scale(g);
  }
  // whb[row*96 + k] = bf16(wh[(g*96+ch)*96 + k] * gate_scale(g)), row = ch*4+g
  for (int idx = tid; idx < 384 * 96; idx += nth) {
    int row = idx / 96, k = idx % 96;
    int ch = row >> 2, g = row & 3;
    whb[idx] = f2bf(wh[((size_t)(g * 96 + ch)) * 96 + k] * gate_scale(g));
  }
  for (int o = tid; o < 128; o += nth) {
    float a = g1[o] / sqrtf(v1[o] + 1e-5f);
    al1[o] = a; be1[o] = b1[o] + (cb1[o] - m1[o]) * a;
  }
  for (int o = tid; o < 96; o += nth) {
    float a = g2[o] / sqrtf(v2[o] + 1e-5f);
    al2[o] = a; be2[o] = b2[o] + (cb2[o] - m2[o]) * a;
    float ar = gr[o] / sqrtf(vr[o] + 1e-5f);
    alr[o] = ar; ber[o] = br[o] + (cbr[o] - mr[o]) * ar;
  }
}

// ---------------- K1: conv1 MFMA implicit GEMM (unchanged) ----------------
__launch_bounds__(256, 2)
__global__ void k_conv1(const float* __restrict__ x, const u16* __restrict__ w1b,
                        const float* __restrict__ al1, const float* __restrict__ be1,
                        u16* __restrict__ out1)
{
  __shared__ __align__(16) u16 xs[134 * 72];
  int tid = threadIdx.x;
  int b = blockIdx.y;
  int t0 = blockIdx.x * 128;
  const float* xb = x + (size_t)b * Tt * Cin;

  for (int idx = tid; idx < 134 * 16; idx += 256) {
    int row = idx >> 4, c4 = (idx & 15) << 2;
    int gt = t0 - 3 + row;
    float4 v = make_float4(0.f, 0.f, 0.f, 0.f);
    if (gt >= 0 && gt < Tt) v = *(const float4*)(xb + (size_t)gt * 64 + c4);
    ushort4 s;
    s.x = f2bf(v.x); s.y = f2bf(v.y); s.z = f2bf(v.z); s.w = f2bf(v.w);
    *(ushort4*)(xs + row * 72 + c4) = s;
  }
  __syncthreads();

  int l = tid & 63;
  int wid = tid >> 6;
  int wm = wid >> 1, wn = wid & 1;
  int lr = l & 15, g = l >> 4;

  f32x4 acc[4][4];
#pragma unroll
  for (int i = 0; i < 4; i++)
#pragma unroll
    for (int j = 0; j < 4; j++) acc[i][j] = (f32x4){0.f, 0.f, 0.f, 0.f};

  const u16* wbase = w1b + (size_t)(wn * 64 + lr) * 448;

  for (int s = 0; s < 14; ++s) {
    int kt = s >> 1;
    int cofs = ((s & 1) << 5) + (g << 3);
    const u16* xrow = xs + (wm * 64 + lr + kt) * 72 + cofs;
    bf16x8 a0 = *(const bf16x8*)(xrow);
    bf16x8 a1 = *(const bf16x8*)(xrow + 16 * 72);
    bf16x8 a2 = *(const bf16x8*)(xrow + 32 * 72);
    bf16x8 a3 = *(const bf16x8*)(xrow + 48 * 72);
    int ko = (s << 5) + (g << 3);
    bf16x8 b0 = *(const bf16x8*)(wbase + ko);
    bf16x8 b1 = *(const bf16x8*)(wbase + 16 * 448 + ko);
    bf16x8 b2 = *(const bf16x8*)(wbase + 32 * 448 + ko);
    bf16x8 b3 = *(const bf16x8*)(wbase + 48 * 448 + ko);
    acc[0][0] = MFMA16(a0, b0, acc[0][0]);
    acc[0][1] = MFMA16(a0, b1, acc[0][1]);
    acc[0][2] = MFMA16(a0, b2, acc[0][2]);
    acc[0][3] = MFMA16(a0, b3, acc[0][3]);
    acc[1][0] = MFMA16(a1, b0, acc[1][0]);
    acc[1][1] = MFMA16(a1, b1, acc[1][1]);
    acc[1][2] = MFMA16(a1, b2, acc[1][2]);
    acc[1][3] = MFMA16(a1, b3, acc[1][3]);
    acc[2][0] = MFMA16(a2, b0, acc[2][0]);
    acc[2][1] = MFMA16(a2, b1, acc[2][1]);
    acc[2][2] = MFMA16(a2, b2, acc[2][2]);
    acc[2][3] = MFMA16(a2, b3, acc[2][3]);
    acc[3][0] = MFMA16(a3, b0, acc[3][0]);
    acc[3][1] = MFMA16(a3, b1, acc[3][1]);
    acc[3][2] = MFMA16(a3, b2, acc[3][2]);
    acc[3][3] = MFMA16(a3, b3, acc[3][3]);
  }

  int colb = wn * 64 + lr;
  int rowb = t0 + wm * 64 + (l >> 4) * 4;
#pragma unroll
  for (int nf = 0; nf < 4; nf++) {
    int col = colb + nf * 16;
    float A = al1[col], Bt = be1[col];
#pragma unroll
    for (int mf = 0; mf < 4; mf++) {
      int row = rowb + mf * 16;
#pragma unroll
      for (int r = 0; r < 4; r++) {
        float v = acc[mf][nf][r];
        v = fmaxf(v * A + Bt, 0.f);
        out1[((size_t)b * Tt + row + r) * 128 + col] = f2bf(v);
      }
    }
  }
}

// ---------------- K2: conv2 MFMA implicit GEMM + fused residual -> seqb bf16 ----------------
__launch_bounds__(256, 4)
__global__ void k_conv2(const u16* __restrict__ out1, const u16* __restrict__ w2b,
                        const u16* __restrict__ wrb,
                        const float* __restrict__ al2, const float* __restrict__ be2,
                        const float* __restrict__ alr, const float* __restrict__ ber,
                        u16* __restrict__ seqb)
{
  int tid = threadIdx.x;
  int b = blockIdx.y;
  int t20 = blockIdx.x * 64;
  int l = tid & 63;
  int wid = tid >> 6;
  int wm = wid >> 1, wn = wid & 1;    // wave tile 32 x 48
  int lr = l & 15, g = l >> 4;

  f32x4 acc[2][3], accr[2][3];
#pragma unroll
  for (int i = 0; i < 2; i++)
#pragma unroll
    for (int j = 0; j < 3; j++) {
      acc[i][j] = (f32x4){0.f, 0.f, 0.f, 0.f};
      accr[i][j] = (f32x4){0.f, 0.f, 0.f, 0.f};
    }

  const u16* ob = out1 + (size_t)b * Tt * 128;
  int colb = wn * 48 + lr;

#pragma unroll
  for (int f = 0; f < 12; f++) {
    int kk = f >> 2;
    int c = ((f & 3) << 5) + (g << 3);
    bf16x8 a[2];
#pragma unroll
    for (int mf = 0; mf < 2; mf++) {
      int t2 = t20 + wm * 32 + mf * 16 + lr;
      int gt = 4 * t2 + kk - 1;
      if (gt >= 0)
        a[mf] = *(const bf16x8*)(ob + (size_t)gt * 128 + c);
      else
        a[mf] = (bf16x8){0, 0, 0, 0, 0, 0, 0, 0};
    }
#pragma unroll
    for (int nf = 0; nf < 3; nf++) {
      int col = colb + nf * 16;
      bf16x8 bb = *(const bf16x8*)(w2b + (size_t)col * 384 + (f << 5) + (g << 3));
      acc[0][nf] = MFMA16(a[0], bb, acc[0][nf]);
      acc[1][nf] = MFMA16(a[1], bb, acc[1][nf]);
    }
    if (kk == 1) {
#pragma unroll
      for (int nf = 0; nf < 3; nf++) {
        int col = colb + nf * 16;
        bf16x8 br = *(const bf16x8*)(wrb + (size_t)col * 128 + ((f & 3) << 5) + (g << 3));
        accr[0][nf] = MFMA16(a[0], br, accr[0][nf]);
        accr[1][nf] = MFMA16(a[1], br, accr[1][nf]);
      }
    }
  }

  int rowb = t20 + wm * 32 + (l >> 4) * 4;
#pragma unroll
  for (int nf = 0; nf < 3; nf++) {
    int col = colb + nf * 16;
    float A = al2[col], Bt = be2[col];
    float Ar = alr[col], Br = ber[col];
#pragma unroll
    for (int mf = 0; mf < 2; mf++) {
      int row = rowb + mf * 16;
#pragma unroll
      for (int r = 0; r < 4; r++) {
        float v = fmaxf(acc[mf][nf][r] * A + Bt, 0.f) + accr[mf][nf][r] * Ar + Br;
        seqb[((size_t)b * T2 + row + r) * 96 + col] = f2bf(v);
      }
    }
  }
}

// ---------------- K4: sLSTM recurrence v8 — fused px MFMA (k_pre removed) ----------------
// 256 threads = 4 waves (1/SIMD), one block per batch.
// Per step: preact = whb x h + wxb x seq(t) + bias, all via MFMA:
//   px(t+1) = MFMA(wxb, seq(t+1), C=biasfrag)  -- computed 1 step ahead (off-chain)
//   acc     = MFMA(whb, h(t),     C=px(t))     -- px is C-in: zero VALU adds
// seq bf16 loaded from global with prefetch distance 2 (2 reg sets, unroll-2).
// Lane (grp,lr<6) owns channel ch=24w+4lr+grp: select acc[lr] via cndmask
// tree, gate math (exp2-domain), write h bf16 to ping-pong hbuf. 1 barrier/step.
__launch_bounds__(256, 1)
__global__ void k_slstm(const u16* __restrict__ seqb, const u16* __restrict__ whb,
                        const u16* __restrict__ wxb, const float* __restrict__ bperm,
                        float* __restrict__ hsum)
{
  __shared__ __align__(16) u16 hbufB[2][96];
  int tid = threadIdx.x;
  int b = blockIdx.x;
  int w = tid >> 6;
  int l = tid & 63;
  int grp = l >> 4, lr = l & 15;

  // A-frags: af (wh), wf (wx): row = 96w + 16m + lr, k = kt*32 + grp*8 + reg
  bf16x8 af[6][3], wf[6][3];
#pragma unroll
  for (int m = 0; m < 6; m++) {
    const u16* wrow = whb + (size_t)(96 * w + 16 * m + lr) * 96 + grp * 8;
    const u16* xrow = wxb + (size_t)(96 * w + 16 * m + lr) * 96 + grp * 8;
#pragma unroll
    for (int kt = 0; kt < 3; kt++) {
      af[m][kt] = *(const bf16x8*)(wrow + kt * 32);
      wf[m][kt] = *(const bf16x8*)(xrow + kt * 32);
    }
  }
  // bias fragment: bias6[m][reg] = bperm[96w + 16m + 4grp + reg]
  f32x4 bias6[6];
#pragma unroll
  for (int m = 0; m < 6; m++)
    bias6[m] = *(const f32x4*)(bperm + 96 * w + 16 * m + 4 * grp);

  bool gl = (lr < 6);
  int ch = 24 * w + 4 * lr + grp;   // valid when gl
  float c = 0.f, n = 0.f, mm = 0.f, hs = 0.f;
  if (tid < 96) hbufB[0][tid] = 0;
  __syncthreads();

  const u16* sqb = seqb + (size_t)b * T2 * 96 + grp * 8;
  bf16x8 sa0, sa1, sa2, sb0, sb1, sb2;
  // s(0) -> sa, compute px(0) -> pxA
  sa0 = *(const bf16x8*)(sqb);
  sa1 = *(const bf16x8*)(sqb + 32);
  sa2 = *(const bf16x8*)(sqb + 64);
  f32x4 pxA[6], pxB[6];
#pragma unroll
  for (int m = 0; m < 6; m++) {
    pxA[m] = MFMA16(wf[m][0], sa0, bias6[m]);
    pxA[m] = MFMA16(wf[m][1], sa1, pxA[m]);
    pxA[m] = MFMA16(wf[m][2], sa2, pxA[m]);
  }
  // s(1) -> sb
  sb0 = *(const bf16x8*)(sqb + 96);
  sb1 = *(const bf16x8*)(sqb + 96 + 32);
  sb2 = *(const bf16x8*)(sqb + 96 + 64);

#define SLSTM_STEP(PXC, PXN, SR0, SR1, SR2, SW0, SW1, SW2, PCUR, TT)           \
  {                                                                            \
    int tld_ = (TT) + 2 < T2 ? (TT) + 2 : T2 - 1;                              \
    const u16* sp_ = sqb + (size_t)tld_ * 96;                                  \
    SW0 = *(const bf16x8*)(sp_);                                               \
    SW1 = *(const bf16x8*)(sp_ + 32);                                          \
    SW2 = *(const bf16x8*)(sp_ + 64);                                          \
    const u16* hb_ = hbufB[PCUR] + grp * 8;                                    \
    bf16x8 h0_ = *(const bf16x8*)(hb_);                                        \
    bf16x8 h1_ = *(const bf16x8*)(hb_ + 32);                                   \
    bf16x8 h2_ = *(const bf16x8*)(hb_ + 64);                                   \
    _Pragma("unroll")                                                          \
    for (int m = 0; m < 6; m++) {                                              \
      PXN[m] = MFMA16(wf[m][0], SR0, bias6[m]);                                \
      PXN[m] = MFMA16(wf[m][1], SR1, PXN[m]);                                  \
      PXN[m] = MFMA16(wf[m][2], SR2, PXN[m]);                                  \
    }                                                                          \
    f32x4 acq_[6];                                                             \
    _Pragma("unroll")                                                          \
    for (int m = 0; m < 6; m++) {                                              \
      acq_[m] = MFMA16(af[m][0], h0_, PXC[m]);                                 \
      acq_[m] = MFMA16(af[m][1], h1_, acq_[m]);                                \
      acq_[m] = MFMA16(af[m][2], h2_, acq_[m]);                                \
    }                                                                          \
    f32x4 x01_ = (lr & 1) ? acq_[1] : acq_[0];                                 \
    f32x4 x23_ = (lr & 1) ? acq_[3] : acq_[2];                                 \
    f32x4 x45_ = (lr & 1) ? acq_[5] : acq_[4];                                 \
    f32x4 y0_ = (lr & 2) ? x23_ : x01_;                                        \
    f32x4 pa_ = (lr & 4) ? x45_ : y0_;                                         \
    if (gl) {                                                                  \
      float zp_ = pa_[0], ip_ = pa_[1], fp_ = pa_[2], op_ = pa_[3];            \
      float zc_ = fminf(fmaxf(zp_, -86.f), 86.f);                              \
      float ez_ = exp2f(zc_);                                                  \
      float z_ = 1.f - 2.f * __builtin_amdgcn_rcpf(ez_ + 1.f);                 \
      float oc_ = fminf(fmaxf(op_, -60.f), 60.f);                              \
      float o_ = __builtin_amdgcn_rcpf(1.f + exp2f(-oc_));                     \
      float mn_ = fmaxf(fp_ + mm, ip_);                                        \
      float iv_ = exp2f(ip_ - mn_);                                            \
      float fv_ = exp2f(fp_ + mm - mn_);                                       \
      c = fv_ * c + iv_ * z_;                                                  \
      n = fv_ * n + iv_;                                                       \
      mm = mn_;                                                                \
      float h_ = o_ * c * __builtin_amdgcn_rcpf(fmaxf(n, 1.f));                \
      hs += h_;                                                                \
      hbufB[(PCUR) ^ 1][ch] = f2bf(h_);                                        \
    }                                                                          \
    __syncthreads();                                                           \
  }

  for (int t = 0; t < T2; t += 2) {
    SLSTM_STEP(pxA, pxB, sb0, sb1, sb2, sa0, sa1, sa2, 0, t);
    SLSTM_STEP(pxB, pxA, sa0, sa1, sa2, sb0, sb1, sb2, 1, t + 1);
  }
#undef SLSTM_STEP

  if (gl) hsum[b * 96 + ch] = hs * (1.f / 1024.f);
}

// ---------------- K5: head (unchanged) ----------------
__launch_bounds__(128)
__global__ void k_head(const float* __restrict__ hsum, const float* __restrict__ fc1w,
                       const float* __restrict__ fc1b, const float* __restrict__ fc2w,
                       const float* __restrict__ fc2b, float* __restrict__ out)
{
  __shared__ float p[96];
  __shared__ float z1[128];
  int tid = threadIdx.x, b = blockIdx.x;
  if (tid < 96) p[tid] = hsum[b * 96 + tid];
  __syncthreads();
  {
    float a = fc1b[tid];
    const float* wr = fc1w + tid * 96;
    for (int h = 0; h < 96; h++) a += p[h] * wr[h];
    z1[tid] = fmaxf(a, 0.f);
  }
  __syncthreads();
  if (tid < NC) {
    float a = fc2b[tid];
    const float* wr = fc2w + tid * 128;
    for (int j = 0; j < 128; j++) a += z1[j] * wr[j];
    out[b * NC + tid] = a;
  }
}

extern "C" void kernel_launch(void* const* d_in, const int* in_sizes, int n_in,
                              void* d_out, int out_size, void* d_ws, size_t ws_size,
                              hipStream_t stream)
{
  const float* x    = (const float*)d_in[0];
  const float* w1   = (const float*)d_in[1];
  const float* cb1  = (const float*)d_in[2];
  const float* g1   = (const float*)d_in[3];
  const float* b1   = (const float*)d_in[4];
  const float* m1   = (const float*)d_in[5];
  const float* v1   = (const float*)d_in[6];
  const float* w2   = (const float*)d_in[7];
  const float* cb2  = (const float*)d_in[8];
  const float* g2   = (const float*)d_in[9];
  const float* b2   = (const float*)d_in[10];
  const float* m2   = (const float*)d_in[11];
  const float* v2   = (const float*)d_in[12];
  const float* wr   = (const float*)d_in[13];
  const float* cbr  = (const float*)d_in[14];
  const float* gr   = (const float*)d_in[15];
  const float* br   = (const float*)d_in[16];
  const float* mr   = (const float*)d_in[17];
  const float* vr   = (const float*)d_in[18];
  const float* wx   = (const float*)d_in[19];
  const float* wh   = (const float*)d_in[20];
  const float* sbia = (const float*)d_in[21];
  const float* fc1w = (const float*)d_in[22];
  const float* fc1b = (const float*)d_in[23];
  const float* fc2w = (const float*)d_in[24];
  const float* fc2b = (const float*)d_in[25];

  char* ws = (char*)d_ws;
  size_t off = 0;
  auto alloc = [&](size_t bytes) -> void* {
    void* p = (void*)(ws + off);
    off = (off + bytes + 255) & ~((size_t)255);
    return p;
  };
  u16*   out1 = (u16*)  alloc((size_t)Bz * Tt * K1c * 2);   // 67.1 MB
  u16*   seqb = (u16*)  alloc((size_t)Bz * T2 * Hh * 2);    // 12.6 MB
  u16*   w1b  = (u16*)  alloc(448 * 128 * 2);
  u16*   w2b  = (u16*)  alloc(96 * 384 * 2);
  u16*   wrb  = (u16*)  alloc(96 * 128 * 2);
  u16*   wxb  = (u16*)  alloc(384 * 96 * 2);
  float* bperm= (float*)alloc(384 * 4);
  u16*   whb  = (u16*)  alloc(384 * 96 * 2);
  float* al1  = (float*)alloc(128 * 4);
  float* be1  = (float*)alloc(128 * 4);
  float* al2  = (float*)alloc(96 * 4);
  float* be2  = (float*)alloc(96 * 4);
  float* alr  = (float*)alloc(96 * 4);
  float* ber  = (float*)alloc(96 * 4);
  float* hsum = (float*)alloc((size_t)Bz * Hh * 4);
  (void)ws_size; (void)in_sizes; (void)n_in; (void)out_size;

  k_prep<<<dim3(224), dim3(256), 0, stream>>>(
      w1, cb1, g1, b1, m1, v1, w2, cb2, g2, b2, m2, v2,
      wr, cbr, gr, br, mr, vr, wx, sbia, wh,
      w1b, w2b, wrb, wxb, bperm, whb, al1, be1, al2, be2, alr, ber);

  k_conv1<<<dim3(Tt / 128, Bz), dim3(256), 0, stream>>>(x, w1b, al1, be1, out1);

  k_conv2<<<dim3(T2 / 64, Bz), dim3(256), 0, stream>>>(out1, w2b, wrb, al2, be2, alr, ber, seqb);

  k_slstm<<<dim3(Bz), dim3(256), 0, stream>>>(seqb, whb, wxb, bperm, hsum);

  k_head<<<dim3(Bz), dim3(128), 0, stream>>>(hsum, fc1w, fc1b, fc2w, fc2b, (float*)d_out);
}